// Round 1
// baseline (1003.078 us; speedup 1.0000x reference)
//
#include <hip/hip_runtime.h>

#define NTOK 4096
#define DM 1024
#define DH 4096
#define NE 8

typedef __attribute__((ext_vector_type(8))) short bf16x8;
typedef __attribute__((ext_vector_type(4))) float f32x4;

__device__ __forceinline__ ushort f2bf(float f) {
  union { float f; unsigned u; } v; v.f = f;
  unsigned r = v.u + 0x7fffu + ((v.u >> 16) & 1u);
  return (ushort)(r >> 16);
}

#define GL2LDS(g, l) __builtin_amdgcn_global_load_lds( \
    (__attribute__((address_space(1))) const void*)(g), \
    (__attribute__((address_space(3))) void*)(l), 16, 0, 0)

// ---------------- gating: logits, top-2, softmax, counts ----------------
__global__ __launch_bounds__(256) void gate_kernel(
    const float* __restrict__ x, const float* __restrict__ Wg,
    const float* __restrict__ bg, int* __restrict__ tkE,
    float* __restrict__ tkW, int* __restrict__ gcnt)
{
  const int wave = threadIdx.x >> 6;
  const int lane = threadIdx.x & 63;
  const int t = blockIdx.x * 4 + wave;

  float acc[NE];
#pragma unroll
  for (int e = 0; e < NE; e++) acc[e] = 0.f;

  for (int i = 0; i < DM / 64; i++) {
    int d = i * 64 + lane;
    float xv = x[(long)t * DM + d];
#pragma unroll
    for (int e = 0; e < NE; e++) acc[e] += xv * Wg[d * NE + e];
  }
#pragma unroll
  for (int e = 0; e < NE; e++) {
#pragma unroll
    for (int off = 32; off; off >>= 1) acc[e] += __shfl_xor(acc[e], off, 64);
    acc[e] += bg[e];
  }
  // top-2 (strict > keeps lowest index on ties, matching jax top_k)
  int e0 = 0; float v0 = acc[0];
#pragma unroll
  for (int e = 1; e < NE; e++) if (acc[e] > v0) { v0 = acc[e]; e0 = e; }
  int e1 = -1; float v1 = -3.4e38f;
#pragma unroll
  for (int e = 0; e < NE; e++) if (e != e0 && acc[e] > v1) { v1 = acc[e]; e1 = e; }
  float w0 = 1.f / (1.f + __expf(v1 - v0));
  float w1 = 1.f - w0;
  if (lane == 0) {
    tkE[t] = e0 | (e1 << 8);
    tkW[2 * t] = w0;
    tkW[2 * t + 1] = w1;
    atomicAdd(&gcnt[e0], 1);
    atomicAdd(&gcnt[e1], 1);
  }
}

// ---------------- exclusive scan of counts (trivial, 8 experts) ----------
__global__ void scan_kernel(const int* __restrict__ gcnt, int* __restrict__ offs,
                            int* __restrict__ cursor)
{
  if (threadIdx.x == 0) {
    int o = 0;
    for (int e = 0; e < NE; e++) { offs[e] = o; o += gcnt[e]; cursor[e] = 0; }
    offs[NE] = o;
  }
}

// ---------------- build packed row lists ----------------
__global__ __launch_bounds__(256) void build_kernel(
    const int* __restrict__ tkE, const float* __restrict__ tkW,
    const int* __restrict__ offs, int* __restrict__ cursor,
    int* __restrict__ rmeta, float* __restrict__ rw)
{
  int t = blockIdx.x * 256 + threadIdx.x;
  int ee = tkE[t];
#pragma unroll
  for (int k = 0; k < 2; k++) {
    int e = (k == 0) ? (ee & 0xff) : (ee >> 8);
    int pos = atomicAdd(&cursor[e], 1);
    int row = offs[e] + pos;
    rmeta[row] = t * 2 + k;
    rw[row] = tkW[t * 2 + k];
  }
}

// ---------------- gather x rows -> packed bf16 A matrix ----------------
__global__ __launch_bounds__(256) void gather_kernel(
    const float* __restrict__ x, const int* __restrict__ rmeta,
    ushort* __restrict__ xg)
{
  int row = blockIdx.x;
  int t = rmeta[row] >> 1;
  const float4* src = (const float4*)(x + (long)t * DM);
  float4 v = src[threadIdx.x];
  ushort4 o = { f2bf(v.x), f2bf(v.y), f2bf(v.z), f2bf(v.w) };
  *(ushort4*)(xg + (long)row * DM + threadIdx.x * 4) = o;
}

// ---------------- transpose + fp32->bf16 convert ----------------
// src: [E][R][C] fp32 (e-stride srcE elems) -> dst: [E][C][R] bf16 (e-stride dstE)
__global__ __launch_bounds__(256) void transpose_cvt(
    const float* __restrict__ src, ushort* __restrict__ dst,
    int R, int C, long srcE, long dstE)
{
  __shared__ float tile[32][33];
  int e = blockIdx.z;
  int c0 = blockIdx.x * 32, r0 = blockIdx.y * 32;
  const float* s = src + (long)e * srcE;
  ushort* d = dst + (long)e * dstE;
  int tx = threadIdx.x;  // 0..31
  int ty = threadIdx.y;  // 0..7
#pragma unroll
  for (int i = 0; i < 32; i += 8)
    tile[ty + i][tx] = s[(long)(r0 + ty + i) * C + c0 + tx];
  __syncthreads();
#pragma unroll
  for (int i = 0; i < 32; i += 8) {
    float v = tile[tx][ty + i];
    d[(long)(c0 + ty + i) * R + r0 + tx] = f2bf(v);
  }
}

// ---------------- GEMM1: xg[rows,1024] x {W0t,W1t}[4096,1024]^ -> a=h*silu(g) ----
__global__ __launch_bounds__(256, 2) void gemm1_kernel(
    const ushort* __restrict__ xg, const ushort* __restrict__ Wt01,
    const float* __restrict__ b0, const float* __restrict__ b1,
    const int* __restrict__ offs, ushort* __restrict__ aout)
{
  const int e = blockIdx.z;
  const int off_e = offs[e];
  const int cnt = offs[e + 1] - off_e;
  const int mt = blockIdx.y;
  if (mt * 128 >= cnt) return;
  const int nbase = blockIdx.x * 128;

  __shared__ ushort As[128 * 32];
  __shared__ ushort Bh[128 * 32];
  __shared__ ushort Bg[128 * 32];

  const int tid = threadIdx.x;
  const int wave = tid >> 6;
  const int lane = tid & 63;
  const int wm = wave & 1;
  const int wn = wave >> 1;

  const ushort* Ap = xg + (long)(off_e + mt * 128) * DM;
  const ushort* Bhp = Wt01 + (long)e * (2 * DH) * DM + (long)nbase * DM;
  const ushort* Bgp = Bhp + (long)DH * DM;

  f32x4 acc_h[4][4], acc_g[4][4];
#pragma unroll
  for (int i = 0; i < 4; i++)
#pragma unroll
    for (int j = 0; j < 4; j++) {
      acc_h[i][j] = (f32x4){0.f, 0.f, 0.f, 0.f};
      acc_g[i][j] = (f32x4){0.f, 0.f, 0.f, 0.f};
    }

  const int soff0 = wave * 1024 + lane * 16;  // bytes within 8192B tile

  for (int k0 = 0; k0 < DM; k0 += 32) {
    __syncthreads();
#pragma unroll
    for (int s = 0; s < 2; s++) {
      int off = s * 4096 + soff0;
      int r = off >> 6;            // tile row (64B per row of 32 bf16)
      int ie = (off & 63) >> 1;    // element within row
      long gelem = (long)r * DM + k0 + ie;
      GL2LDS(Ap + gelem, (char*)As + off);
      GL2LDS(Bhp + gelem, (char*)Bh + off);
      GL2LDS(Bgp + gelem, (char*)Bg + off);
    }
    __syncthreads();

    bf16x8 af[4], bhf[4], bgf[4];
#pragma unroll
    for (int i = 0; i < 4; i++) {
      int ro = (i * 16 + (lane & 15)) * 32 + (lane >> 4) * 8;
      af[i]  = *(const bf16x8*)&As[(wm * 64) * 32 + ro];
      bhf[i] = *(const bf16x8*)&Bh[(wn * 64) * 32 + ro];
      bgf[i] = *(const bf16x8*)&Bg[(wn * 64) * 32 + ro];
    }
#pragma unroll
    for (int i = 0; i < 4; i++)
#pragma unroll
      for (int j = 0; j < 4; j++) {
        acc_h[i][j] = __builtin_amdgcn_mfma_f32_16x16x32_bf16(af[i], bhf[j], acc_h[i][j], 0, 0, 0);
        acc_g[i][j] = __builtin_amdgcn_mfma_f32_16x16x32_bf16(af[i], bgf[j], acc_g[i][j], 0, 0, 0);
      }
  }

#pragma unroll
  for (int j = 0; j < 4; j++) {
    const int col = nbase + wn * 64 + j * 16 + (lane & 15);
    const float bb0 = b0[e * DH + col];
    const float bb1 = b1[e * DH + col];
#pragma unroll
    for (int i = 0; i < 4; i++) {
#pragma unroll
      for (int r = 0; r < 4; r++) {
        int mlocal = mt * 128 + wm * 64 + i * 16 + (lane >> 4) * 4 + r;
        if (mlocal < cnt) {
          float h = acc_h[i][j][r] + bb0;
          float g = acc_g[i][j][r] + bb1;
          float a = h * (g / (1.f + __expf(-g)));
          aout[(long)(off_e + mlocal) * DH + col] = f2bf(a);
        }
      }
    }
  }
}

// ---------------- GEMM2: a[rows,4096] x W2t[1024,4096]^ -> w * y -> ybuf ----
__global__ __launch_bounds__(256, 2) void gemm2_kernel(
    const ushort* __restrict__ aout, const ushort* __restrict__ W2t,
    const float* __restrict__ b2, const int* __restrict__ offs,
    const int* __restrict__ rmeta, const float* __restrict__ rw,
    float* __restrict__ ybuf)
{
  const int e = blockIdx.z;
  const int off_e = offs[e];
  const int cnt = offs[e + 1] - off_e;
  const int mt = blockIdx.y;
  if (mt * 128 >= cnt) return;
  const int nbase = blockIdx.x * 128;

  __shared__ ushort As[128 * 32];
  __shared__ ushort Bs[128 * 32];

  const int tid = threadIdx.x;
  const int wave = tid >> 6;
  const int lane = tid & 63;
  const int wm = wave & 1;
  const int wn = wave >> 1;

  const ushort* Ap = aout + (long)(off_e + mt * 128) * DH;
  const ushort* Bp = W2t + (long)e * DM * DH + (long)nbase * DH;

  f32x4 acc[4][4];
#pragma unroll
  for (int i = 0; i < 4; i++)
#pragma unroll
    for (int j = 0; j < 4; j++) acc[i][j] = (f32x4){0.f, 0.f, 0.f, 0.f};

  const int soff0 = wave * 1024 + lane * 16;

  for (int k0 = 0; k0 < DH; k0 += 32) {
    __syncthreads();
#pragma unroll
    for (int s = 0; s < 2; s++) {
      int off = s * 4096 + soff0;
      int r = off >> 6;
      int ie = (off & 63) >> 1;
      long gelem = (long)r * DH + k0 + ie;
      GL2LDS(Ap + gelem, (char*)As + off);
      GL2LDS(Bp + gelem, (char*)Bs + off);
    }
    __syncthreads();

    bf16x8 af[4], bf[4];
#pragma unroll
    for (int i = 0; i < 4; i++) {
      int ro = (i * 16 + (lane & 15)) * 32 + (lane >> 4) * 8;
      af[i] = *(const bf16x8*)&As[(wm * 64) * 32 + ro];
      bf[i] = *(const bf16x8*)&Bs[(wn * 64) * 32 + ro];
    }
#pragma unroll
    for (int i = 0; i < 4; i++)
#pragma unroll
      for (int j = 0; j < 4; j++)
        acc[i][j] = __builtin_amdgcn_mfma_f32_16x16x32_bf16(af[i], bf[j], acc[i][j], 0, 0, 0);
  }

#pragma unroll
  for (int j = 0; j < 4; j++) {
    const int col = nbase + wn * 64 + j * 16 + (lane & 15);
    const float bb2 = b2[e * DM + col];
#pragma unroll
    for (int i = 0; i < 4; i++) {
#pragma unroll
      for (int r = 0; r < 4; r++) {
        int mlocal = mt * 128 + wm * 64 + i * 16 + (lane >> 4) * 4 + r;
        if (mlocal < cnt) {
          int grow = off_e + mlocal;
          float y = acc[i][j][r] + bb2;
          ybuf[(long)rmeta[grow] * DM + col] = rw[grow] * y;
        }
      }
    }
  }
}

// ---------------- combine the two expert outputs per token ----------------
__global__ __launch_bounds__(256) void combine_kernel(
    const float* __restrict__ ybuf, float* __restrict__ out)
{
  int idx = blockIdx.x * 256 + threadIdx.x;  // one float4 per thread
  int t = idx >> 8;
  int c = (idx & 255) * 4;
  const float4 a = *(const float4*)&ybuf[(long)(2 * t) * DM + c];
  const float4 b = *(const float4*)&ybuf[(long)(2 * t + 1) * DM + c];
  float4 o = { a.x + b.x, a.y + b.y, a.z + b.z, a.w + b.w };
  *(float4*)&out[(long)t * DM + c] = o;
}

extern "C" void kernel_launch(void* const* d_in, const int* in_sizes, int n_in,
                              void* d_out, int out_size, void* d_ws, size_t ws_size,
                              hipStream_t stream) {
  const float* x  = (const float*)d_in[0];
  const float* Wg = (const float*)d_in[1];
  const float* bg = (const float*)d_in[2];
  const float* W0 = (const float*)d_in[3];
  const float* b0 = (const float*)d_in[4];
  const float* W1 = (const float*)d_in[5];
  const float* b1 = (const float*)d_in[6];
  const float* W2 = (const float*)d_in[7];
  const float* b2 = (const float*)d_in[8];
  float* out = (float*)d_out;

  char* ws = (char*)d_ws;
  // workspace layout (bytes, all 256-aligned); total ~320.2 MB
  ushort* Wt01 = (ushort*)(ws + 0);           // [8][8192][1024] bf16 = 134217728
  ushort* W2t  = (ushort*)(ws + 134217728);   // [8][1024][4096] bf16 = 67108864
  ushort* xg   = (ushort*)(ws + 201326592);   // [8320][1024] bf16   = 17039360
  ushort* aout = (ushort*)(ws + 218365952);   // [8320][4096] bf16   = 68157440
  float*  ybuf = (float*)(ws + 286523392);    // [8192][1024] f32    = 33554432
  int*    tkE  = (int*)(ws + 320077824);      // [4096]
  float*  tkW  = (float*)(ws + 320094208);    // [8192]
  int*    rmeta= (int*)(ws + 320126976);      // [8320]
  float*  rw   = (float*)(ws + 320160256);    // [8320]
  int*    gcnt = (int*)(ws + 320193536);      // [8]
  int*    offs = gcnt + 8;                    // [9]
  int*    cursor = gcnt + 20;                 // [8]

  hipMemsetAsync(gcnt, 0, 32, stream);
  gate_kernel<<<NTOK / 4, 256, 0, stream>>>(x, Wg, bg, tkE, tkW, gcnt);
  scan_kernel<<<1, 64, 0, stream>>>(gcnt, offs, cursor);
  build_kernel<<<NTOK / 256, 256, 0, stream>>>(tkE, tkW, offs, cursor, rmeta, rw);
  gather_kernel<<<2 * NTOK, 256, 0, stream>>>(x, rmeta, xg);

  // W0 -> Wt01[e][0:4096][k], W1 -> Wt01[e][4096:8192][k], W2 -> W2t[e][d][h]
  transpose_cvt<<<dim3(128, 32, 8), dim3(32, 8), 0, stream>>>(
      W0, Wt01, 1024, 4096, (long)1024 * 4096, (long)8192 * 1024);
  transpose_cvt<<<dim3(128, 32, 8), dim3(32, 8), 0, stream>>>(
      W1, Wt01 + (long)4096 * 1024, 1024, 4096, (long)1024 * 4096, (long)8192 * 1024);
  transpose_cvt<<<dim3(32, 128, 8), dim3(32, 8), 0, stream>>>(
      W2, W2t, 4096, 1024, (long)4096 * 1024, (long)1024 * 4096);

  gemm1_kernel<<<dim3(32, 32, 8), 256, 0, stream>>>(xg, Wt01, b0, b1, offs, aout);
  gemm2_kernel<<<dim3(8, 32, 8), 256, 0, stream>>>(aout, W2t, b2, offs, rmeta, rw, ybuf);
  combine_kernel<<<dim3(NTOK), 256, 0, stream>>>(ybuf, out);
}

// Round 2
// 973.645 us; speedup vs baseline: 1.0302x; 1.0302x over previous
//
#include <hip/hip_runtime.h>

#define NTOK 4096
#define DM 1024
#define DH 4096
#define NE 8

typedef __attribute__((ext_vector_type(8))) short bf16x8;
typedef __attribute__((ext_vector_type(4))) float f32x4;
typedef __attribute__((ext_vector_type(8))) unsigned short u16x8;

__device__ __forceinline__ ushort f2bf(float f) {
  union { float f; unsigned u; } v; v.f = f;
  unsigned r = v.u + 0x7fffu + ((v.u >> 16) & 1u);
  return (ushort)(r >> 16);
}

#define GL2LDS(g, l) __builtin_amdgcn_global_load_lds( \
    (__attribute__((address_space(1))) const void*)(g), \
    (__attribute__((address_space(3))) void*)(l), 16, 0, 0)

// ---------------- gating: logits, top-2, softmax, counts ----------------
__global__ __launch_bounds__(256) void gate_kernel(
    const float* __restrict__ x, const float* __restrict__ Wg,
    const float* __restrict__ bg, int* __restrict__ tkE,
    float* __restrict__ tkW, int* __restrict__ gcnt)
{
  const int wave = threadIdx.x >> 6;
  const int lane = threadIdx.x & 63;
  const int t = blockIdx.x * 4 + wave;

  float acc[NE];
#pragma unroll
  for (int e = 0; e < NE; e++) acc[e] = 0.f;

  for (int i = 0; i < DM / 64; i++) {
    int d = i * 64 + lane;
    float xv = x[(long)t * DM + d];
#pragma unroll
    for (int e = 0; e < NE; e++) acc[e] += xv * Wg[d * NE + e];
  }
#pragma unroll
  for (int e = 0; e < NE; e++) {
#pragma unroll
    for (int off = 32; off; off >>= 1) acc[e] += __shfl_xor(acc[e], off, 64);
    acc[e] += bg[e];
  }
  int e0 = 0; float v0 = acc[0];
#pragma unroll
  for (int e = 1; e < NE; e++) if (acc[e] > v0) { v0 = acc[e]; e0 = e; }
  int e1 = -1; float v1 = -3.4e38f;
#pragma unroll
  for (int e = 0; e < NE; e++) if (e != e0 && acc[e] > v1) { v1 = acc[e]; e1 = e; }
  float w0 = 1.f / (1.f + __expf(v1 - v0));
  float w1 = 1.f - w0;
  if (lane == 0) {
    tkE[t] = e0 | (e1 << 8);
    tkW[2 * t] = w0;
    tkW[2 * t + 1] = w1;
    atomicAdd(&gcnt[e0], 1);
    atomicAdd(&gcnt[e1], 1);
  }
}

// ---------------- exclusive scan of counts ----------
__global__ void scan_kernel(const int* __restrict__ gcnt, int* __restrict__ offs,
                            int* __restrict__ cursor)
{
  if (threadIdx.x == 0) {
    int o = 0;
    for (int e = 0; e < NE; e++) { offs[e] = o; o += gcnt[e]; cursor[e] = 0; }
    offs[NE] = o;
  }
}

// ---------------- build packed row lists ----------------
__global__ __launch_bounds__(256) void build_kernel(
    const int* __restrict__ tkE, const float* __restrict__ tkW,
    const int* __restrict__ offs, int* __restrict__ cursor,
    int* __restrict__ rmeta, float* __restrict__ rw)
{
  int t = blockIdx.x * 256 + threadIdx.x;
  int ee = tkE[t];
#pragma unroll
  for (int k = 0; k < 2; k++) {
    int e = (k == 0) ? (ee & 0xff) : (ee >> 8);
    int pos = atomicAdd(&cursor[e], 1);
    int row = offs[e] + pos;
    rmeta[row] = t * 2 + k;
    rw[row] = tkW[t * 2 + k];
  }
}

// ---------------- gather x rows -> packed bf16 A matrix ----------------
__global__ __launch_bounds__(256) void gather_kernel(
    const float* __restrict__ x, const int* __restrict__ rmeta,
    ushort* __restrict__ xg)
{
  int row = blockIdx.x;
  int t = rmeta[row] >> 1;
  const float4* src = (const float4*)(x + (long)t * DM);
  float4 v = src[threadIdx.x];
  ushort4 o = { f2bf(v.x), f2bf(v.y), f2bf(v.z), f2bf(v.w) };
  *(ushort4*)(xg + (long)row * DM + threadIdx.x * 4) = o;
}

// ---------------- transpose + fp32->bf16 convert (vectorized) ----------
// src: [E][R][C] fp32 -> dst: [E][C][R] bf16.  Tile: 32 R-rows x 128 C-cols.
// LDS row stride 132 floats: 16B-aligned rows (528B), conflict-free b128
// writes; transposed reads are 2-way (free, m136).
__global__ __launch_bounds__(256) void transpose_cvt(
    const float* __restrict__ src, ushort* __restrict__ dst,
    int R, int C, long srcE, long dstE)
{
  __shared__ __align__(16) float tile[32][132];
  const int e = blockIdx.z;
  const int r0 = blockIdx.y * 32;
  const int c0 = blockIdx.x * 128;
  const float* s = src + (long)e * srcE;
  ushort* d = dst + (long)e * dstE;
  const int tid = threadIdx.x;
  const int lr = tid >> 5;   // 0..7
  const int lc4 = tid & 31;  // 0..31 (float4 index)
#pragma unroll
  for (int p = 0; p < 4; p++) {
    int r = p * 8 + lr;
    float4 v = *(const float4*)&s[(long)(r0 + r) * C + c0 + lc4 * 4];
    *(float4*)&tile[r][lc4 * 4] = v;
  }
  __syncthreads();
  const int oc = tid >> 1;    // 0..127 (output row = input col)
  const int half = tid & 1;   // r-subrange
  u16x8 o0, o1;
#pragma unroll
  for (int j = 0; j < 8; j++) {
    o0[j] = f2bf(tile[half * 16 + j][oc]);
    o1[j] = f2bf(tile[half * 16 + 8 + j][oc]);
  }
  ushort* dp = &d[(long)(c0 + oc) * R + r0 + half * 16];
  *(u16x8*)dp = o0;
  *(u16x8*)(dp + 8) = o1;
}

// ---------------- GEMM1: xg[rows,1024] x {W0t,W1t} -> a=h*silu(g) ----
// XCD swizzle: all m-tiles of one (e,nt) share flat%8 -> same XCD -> the
// 512KB B slab stays in that XCD's 4MB L2.
__global__ __launch_bounds__(256, 2) void gemm1_kernel(
    const ushort* __restrict__ xg, const ushort* __restrict__ Wt01,
    const float* __restrict__ b0, const float* __restrict__ b1,
    const int* __restrict__ offs, ushort* __restrict__ aout)
{
  const int flat = blockIdx.x + 32 * (blockIdx.y + 32 * blockIdx.z);
  const int xcd = flat & 7;
  const int s_ = flat >> 3;      // 0..1023
  const int grp = s_ >> 5;       // 0..31
  const int mt = s_ & 31;
  const int gid = grp * 8 + xcd; // 0..255
  const int e = gid >> 5;
  const int nt = gid & 31;

  const int off_e = offs[e];
  const int cnt = offs[e + 1] - off_e;
  if (mt * 128 >= cnt) return;
  const int nbase = nt * 128;

  __shared__ ushort As[128 * 32];
  __shared__ ushort Bh[128 * 32];
  __shared__ ushort Bg[128 * 32];

  const int tid = threadIdx.x;
  const int wave = tid >> 6;
  const int lane = tid & 63;
  const int wm = wave & 1;
  const int wn = wave >> 1;

  const ushort* Ap = xg + (long)(off_e + mt * 128) * DM;
  const ushort* Bhp = Wt01 + (long)e * (2 * DH) * DM + (long)nbase * DM;
  const ushort* Bgp = Bhp + (long)DH * DM;

  f32x4 acc_h[4][4], acc_g[4][4];
#pragma unroll
  for (int i = 0; i < 4; i++)
#pragma unroll
    for (int j = 0; j < 4; j++) {
      acc_h[i][j] = (f32x4){0.f, 0.f, 0.f, 0.f};
      acc_g[i][j] = (f32x4){0.f, 0.f, 0.f, 0.f};
    }

  const int soff0 = wave * 1024 + lane * 16;  // bytes within 8192B tile

  for (int k0 = 0; k0 < DM; k0 += 32) {
    __syncthreads();
#pragma unroll
    for (int s = 0; s < 2; s++) {
      int off = s * 4096 + soff0;
      int r = off >> 6;
      int ie = (off & 63) >> 1;
      long gelem = (long)r * DM + k0 + ie;
      GL2LDS(Ap + gelem, (char*)As + off);
      GL2LDS(Bhp + gelem, (char*)Bh + off);
      GL2LDS(Bgp + gelem, (char*)Bg + off);
    }
    __syncthreads();

    bf16x8 af[4], bhf[4], bgf[4];
#pragma unroll
    for (int i = 0; i < 4; i++) {
      int ro = (i * 16 + (lane & 15)) * 32 + (lane >> 4) * 8;
      af[i]  = *(const bf16x8*)&As[(wm * 64) * 32 + ro];
      bhf[i] = *(const bf16x8*)&Bh[(wn * 64) * 32 + ro];
      bgf[i] = *(const bf16x8*)&Bg[(wn * 64) * 32 + ro];
    }
#pragma unroll
    for (int i = 0; i < 4; i++)
#pragma unroll
      for (int j = 0; j < 4; j++) {
        acc_h[i][j] = __builtin_amdgcn_mfma_f32_16x16x32_bf16(af[i], bhf[j], acc_h[i][j], 0, 0, 0);
        acc_g[i][j] = __builtin_amdgcn_mfma_f32_16x16x32_bf16(af[i], bgf[j], acc_g[i][j], 0, 0, 0);
      }
  }

#pragma unroll
  for (int j = 0; j < 4; j++) {
    const int col = nbase + wn * 64 + j * 16 + (lane & 15);
    const float bb0 = b0[e * DH + col];
    const float bb1 = b1[e * DH + col];
#pragma unroll
    for (int i = 0; i < 4; i++) {
#pragma unroll
      for (int r = 0; r < 4; r++) {
        int mlocal = mt * 128 + wm * 64 + i * 16 + (lane >> 4) * 4 + r;
        if (mlocal < cnt) {
          float h = acc_h[i][j][r] + bb0;
          float g = acc_g[i][j][r] + bb1;
          float a = h * (g / (1.f + __expf(-g)));
          aout[(long)(off_e + mlocal) * DH + col] = f2bf(a);
        }
      }
    }
  }
}

// ---------------- GEMM2 (split-K=2): a[rows,4096] x W2t -> partials ----
// Partial kc sums k in [kc*2048, kc*2048+2048); rw-scaled rows written to
// ybuf[kc][tslot][col] (no bias here; combine adds w_k*b2[e_k]).
__global__ __launch_bounds__(256, 2) void gemm2_kernel(
    const ushort* __restrict__ aout, const ushort* __restrict__ W2t,
    const int* __restrict__ offs, const int* __restrict__ rmeta,
    const float* __restrict__ rw, float* __restrict__ ybuf)
{
  const int flat = blockIdx.x + 16 * (blockIdx.y + 32 * blockIdx.z);
  const int xcd = flat & 7;
  const int s_ = flat >> 3;      // 0..511
  const int grp = s_ >> 5;       // 0..15
  const int mt = s_ & 31;
  const int gid = grp * 8 + xcd; // 0..127
  const int e = gid >> 4;
  const int rest = gid & 15;
  const int nt = rest >> 1;      // 0..7
  const int kc = rest & 1;

  const int off_e = offs[e];
  const int cnt = offs[e + 1] - off_e;
  if (mt * 128 >= cnt) return;
  const int nbase = nt * 128;

  __shared__ ushort As[128 * 32];
  __shared__ ushort Bs[128 * 32];

  const int tid = threadIdx.x;
  const int wave = tid >> 6;
  const int lane = tid & 63;
  const int wm = wave & 1;
  const int wn = wave >> 1;

  const ushort* Ap = aout + (long)(off_e + mt * 128) * DH;
  const ushort* Bp = W2t + (long)e * DM * DH + (long)nbase * DH;

  f32x4 acc[4][4];
#pragma unroll
  for (int i = 0; i < 4; i++)
#pragma unroll
    for (int j = 0; j < 4; j++) acc[i][j] = (f32x4){0.f, 0.f, 0.f, 0.f};

  const int soff0 = wave * 1024 + lane * 16;
  const int kbase = kc * 2048;

  for (int k0 = kbase; k0 < kbase + 2048; k0 += 32) {
    __syncthreads();
#pragma unroll
    for (int s = 0; s < 2; s++) {
      int off = s * 4096 + soff0;
      int r = off >> 6;
      int ie = (off & 63) >> 1;
      long gelem = (long)r * DH + k0 + ie;
      GL2LDS(Ap + gelem, (char*)As + off);
      GL2LDS(Bp + gelem, (char*)Bs + off);
    }
    __syncthreads();

    bf16x8 af[4], bfr[4];
#pragma unroll
    for (int i = 0; i < 4; i++) {
      int ro = (i * 16 + (lane & 15)) * 32 + (lane >> 4) * 8;
      af[i]  = *(const bf16x8*)&As[(wm * 64) * 32 + ro];
      bfr[i] = *(const bf16x8*)&Bs[(wn * 64) * 32 + ro];
    }
#pragma unroll
    for (int i = 0; i < 4; i++)
#pragma unroll
      for (int j = 0; j < 4; j++)
        acc[i][j] = __builtin_amdgcn_mfma_f32_16x16x32_bf16(af[i], bfr[j], acc[i][j], 0, 0, 0);
  }

#pragma unroll
  for (int j = 0; j < 4; j++) {
    const int col = nbase + wn * 64 + j * 16 + (lane & 15);
#pragma unroll
    for (int i = 0; i < 4; i++) {
#pragma unroll
      for (int r = 0; r < 4; r++) {
        int mlocal = mt * 128 + wm * 64 + i * 16 + (lane >> 4) * 4 + r;
        if (mlocal < cnt) {
          int grow = off_e + mlocal;
          ybuf[((long)kc * 8192 + rmeta[grow]) * DM + col] = rw[grow] * acc[i][j][r];
        }
      }
    }
  }
}

// ---------------- combine: split-K partials + both experts + bias ----------
__global__ __launch_bounds__(256) void combine_kernel(
    const float* __restrict__ ybuf, const int* __restrict__ tkE,
    const float* __restrict__ tkW, const float* __restrict__ b2,
    float* __restrict__ out)
{
  const int t = blockIdx.x;
  const int c = threadIdx.x * 4;
  const int ee = tkE[t];
  const int e0 = ee & 0xff, e1 = ee >> 8;
  const float w0 = tkW[2 * t], w1 = tkW[2 * t + 1];

  float4 acc = {0.f, 0.f, 0.f, 0.f};
#pragma unroll
  for (int kc = 0; kc < 2; kc++) {
#pragma unroll
    for (int k = 0; k < 2; k++) {
      const float4 v = *(const float4*)&ybuf[((long)kc * 8192 + 2 * t + k) * DM + c];
      acc.x += v.x; acc.y += v.y; acc.z += v.z; acc.w += v.w;
    }
  }
  const float4 p0 = *(const float4*)&b2[(long)e0 * DM + c];
  const float4 p1 = *(const float4*)&b2[(long)e1 * DM + c];
  acc.x += w0 * p0.x + w1 * p1.x;
  acc.y += w0 * p0.y + w1 * p1.y;
  acc.z += w0 * p0.z + w1 * p1.z;
  acc.w += w0 * p0.w + w1 * p1.w;
  *(float4*)&out[(long)t * DM + c] = acc;
}

extern "C" void kernel_launch(void* const* d_in, const int* in_sizes, int n_in,
                              void* d_out, int out_size, void* d_ws, size_t ws_size,
                              hipStream_t stream) {
  const float* x  = (const float*)d_in[0];
  const float* Wg = (const float*)d_in[1];
  const float* bg = (const float*)d_in[2];
  const float* W0 = (const float*)d_in[3];
  const float* b0 = (const float*)d_in[4];
  const float* W1 = (const float*)d_in[5];
  const float* b1 = (const float*)d_in[6];
  const float* W2 = (const float*)d_in[7];
  const float* b2 = (const float*)d_in[8];
  float* out = (float*)d_out;

  char* ws = (char*)d_ws;
  // ybuf ALIASES Wt01: Wt01 is dead after gemm1; ybuf written by gemm2 after.
  ushort* Wt01 = (ushort*)(ws + 0);           // [8][8192][1024] bf16 = 134217728
  float*  ybuf = (float*)(ws + 0);            // [2][8192][1024] f32 =  67108864
  ushort* W2t  = (ushort*)(ws + 134217728);   // [8][1024][4096] bf16 = 67108864
  ushort* xg   = (ushort*)(ws + 201326592);   // [8320][1024] bf16
  ushort* aout = (ushort*)(ws + 218365952);   // [8320][4096] bf16
  int*    tkE  = (int*)(ws + 320077824);
  float*  tkW  = (float*)(ws + 320094208);
  int*    rmeta= (int*)(ws + 320126976);
  float*  rw   = (float*)(ws + 320160256);
  int*    gcnt = (int*)(ws + 320193536);
  int*    offs = gcnt + 8;
  int*    cursor = gcnt + 20;

  hipMemsetAsync(gcnt, 0, 32, stream);
  gate_kernel<<<NTOK / 4, 256, 0, stream>>>(x, Wg, bg, tkE, tkW, gcnt);
  scan_kernel<<<1, 64, 0, stream>>>(gcnt, offs, cursor);
  build_kernel<<<NTOK / 256, 256, 0, stream>>>(tkE, tkW, offs, cursor, rmeta, rw);
  gather_kernel<<<2 * NTOK, 256, 0, stream>>>(x, rmeta, xg);

  transpose_cvt<<<dim3(32, 32, 8), 256, 0, stream>>>(
      W0, Wt01, 1024, 4096, (long)1024 * 4096, (long)8192 * 1024);
  transpose_cvt<<<dim3(32, 32, 8), 256, 0, stream>>>(
      W1, Wt01 + (long)4096 * 1024, 1024, 4096, (long)1024 * 4096, (long)8192 * 1024);
  transpose_cvt<<<dim3(8, 128, 8), 256, 0, stream>>>(
      W2, W2t, 4096, 1024, (long)4096 * 1024, (long)1024 * 4096);

  gemm1_kernel<<<dim3(32, 32, 8), 256, 0, stream>>>(xg, Wt01, b0, b1, offs, aout);
  gemm2_kernel<<<dim3(16, 32, 8), 256, 0, stream>>>(aout, W2t, offs, rmeta, rw, ybuf);
  combine_kernel<<<dim3(NTOK), 256, 0, stream>>>(ybuf, tkE, tkW, b2, out);
}

// Round 3
// 929.847 us; speedup vs baseline: 1.0788x; 1.0471x over previous
//
#include <hip/hip_runtime.h>

#define NTOK 4096
#define DM 1024
#define DH 4096
#define NE 8

typedef __attribute__((ext_vector_type(8))) short bf16x8;
typedef __attribute__((ext_vector_type(4))) float f32x4;
typedef __attribute__((ext_vector_type(8))) unsigned short u16x8;

__device__ __forceinline__ ushort f2bf(float f) {
  union { float f; unsigned u; } v; v.f = f;
  unsigned r = v.u + 0x7fffu + ((v.u >> 16) & 1u);
  return (ushort)(r >> 16);
}

#define GL2LDS(g, l) __builtin_amdgcn_global_load_lds( \
    (__attribute__((address_space(1))) const void*)(g), \
    (__attribute__((address_space(3))) void*)(l), 16, 0, 0)

// ---------------- gating: logits, top-2, softmax, counts ----------------
__global__ __launch_bounds__(256) void gate_kernel(
    const float* __restrict__ x, const float* __restrict__ Wg,
    const float* __restrict__ bg, int* __restrict__ tkE,
    float* __restrict__ tkW, int* __restrict__ gcnt)
{
  const int wave = threadIdx.x >> 6;
  const int lane = threadIdx.x & 63;
  const int t = blockIdx.x * 4 + wave;

  float acc[NE];
#pragma unroll
  for (int e = 0; e < NE; e++) acc[e] = 0.f;

  for (int i = 0; i < DM / 64; i++) {
    int d = i * 64 + lane;
    float xv = x[(long)t * DM + d];
#pragma unroll
    for (int e = 0; e < NE; e++) acc[e] += xv * Wg[d * NE + e];
  }
#pragma unroll
  for (int e = 0; e < NE; e++) {
#pragma unroll
    for (int off = 32; off; off >>= 1) acc[e] += __shfl_xor(acc[e], off, 64);
    acc[e] += bg[e];
  }
  int e0 = 0; float v0 = acc[0];
#pragma unroll
  for (int e = 1; e < NE; e++) if (acc[e] > v0) { v0 = acc[e]; e0 = e; }
  int e1 = -1; float v1 = -3.4e38f;
#pragma unroll
  for (int e = 0; e < NE; e++) if (e != e0 && acc[e] > v1) { v1 = acc[e]; e1 = e; }
  float w0 = 1.f / (1.f + __expf(v1 - v0));
  float w1 = 1.f - w0;
  if (lane == 0) {
    tkE[t] = e0 | (e1 << 8);
    tkW[2 * t] = w0;
    tkW[2 * t + 1] = w1;
    atomicAdd(&gcnt[e0], 1);
    atomicAdd(&gcnt[e1], 1);
  }
}

// ---------------- exclusive scan of counts ----------
__global__ void scan_kernel(const int* __restrict__ gcnt, int* __restrict__ offs,
                            int* __restrict__ cursor)
{
  if (threadIdx.x == 0) {
    int o = 0;
    for (int e = 0; e < NE; e++) { offs[e] = o; o += gcnt[e]; cursor[e] = 0; }
    offs[NE] = o;
  }
}

// ---------------- build packed row lists ----------------
__global__ __launch_bounds__(256) void build_kernel(
    const int* __restrict__ tkE, const float* __restrict__ tkW,
    const int* __restrict__ offs, int* __restrict__ cursor,
    int* __restrict__ rmeta, float* __restrict__ rw)
{
  int t = blockIdx.x * 256 + threadIdx.x;
  int ee = tkE[t];
#pragma unroll
  for (int k = 0; k < 2; k++) {
    int e = (k == 0) ? (ee & 0xff) : (ee >> 8);
    int pos = atomicAdd(&cursor[e], 1);
    int row = offs[e] + pos;
    rmeta[row] = t * 2 + k;
    rw[row] = tkW[t * 2 + k];
  }
}

// ---------------- gather x rows -> packed bf16 A matrix ----------------
__global__ __launch_bounds__(256) void gather_kernel(
    const float* __restrict__ x, const int* __restrict__ rmeta,
    ushort* __restrict__ xg)
{
  int row = blockIdx.x;
  int t = rmeta[row] >> 1;
  const float4* src = (const float4*)(x + (long)t * DM);
  float4 v = src[threadIdx.x];
  ushort4 o = { f2bf(v.x), f2bf(v.y), f2bf(v.z), f2bf(v.w) };
  *(ushort4*)(xg + (long)row * DM + threadIdx.x * 4) = o;
}

// ---------------- transpose + fp32->bf16 convert (64x64 tiles) ----------
// src: [E][R][C] fp32 -> dst: [E][C][R] bf16. Reads: float4 coalesced.
// Writes: each wave emits 128B contiguous per output row (2x 16B/thread).
__global__ __launch_bounds__(256) void transpose_cvt(
    const float* __restrict__ src, ushort* __restrict__ dst,
    int R, int C, long srcE, long dstE)
{
  __shared__ __align__(16) float tile[64][68];
  const int e = blockIdx.z;
  const int r0 = blockIdx.y * 64;
  const int c0 = blockIdx.x * 64;
  const float* s = src + (long)e * srcE;
  ushort* d = dst + (long)e * dstE;
  const int tid = threadIdx.x;
  const int lr = tid >> 4;      // 0..15
  const int lc4 = tid & 15;     // float4 col 0..15
#pragma unroll
  for (int p = 0; p < 4; p++) {
    int r = p * 16 + lr;
    float4 v = *(const float4*)&s[(long)(r0 + r) * C + c0 + lc4 * 4];
    *(float4*)&tile[r][lc4 * 4] = v;
  }
  __syncthreads();
  const int oc = tid >> 2;      // output row (= src col) 0..63
  const int seg = tid & 3;      // 16B segment
  u16x8 o0, o1;
#pragma unroll
  for (int j = 0; j < 8; j++) {
    o0[j] = f2bf(tile[seg * 8 + j][oc]);
    o1[j] = f2bf(tile[32 + seg * 8 + j][oc]);
  }
  ushort* dp = &d[(long)(c0 + oc) * R + r0];
  *(u16x8*)(dp + seg * 8) = o0;
  *(u16x8*)(dp + 32 + seg * 8) = o1;
}

// ---------------- GEMM1: xg[rows,1024] x {W0t,W1t} -> a=h*silu(g) ----
// 128m x 64n block, per-wave 64x32 dual acc (16 f32x4 = 64 AGPR) so 3
// waves/SIMD fit (~164 regs). XCD swizzle keeps one (e,nt) B-slab per XCD L2.
__global__ __launch_bounds__(256, 3) void gemm1_kernel(
    const ushort* __restrict__ xg, const ushort* __restrict__ Wt01,
    const float* __restrict__ b0, const float* __restrict__ b1,
    const int* __restrict__ offs, ushort* __restrict__ aout)
{
  const int flat = blockIdx.x + 16 * (blockIdx.y + 64 * blockIdx.z);
  const int xcd = flat & 7;
  const int s_ = flat >> 3;      // 0..1023
  const int mt = s_ & 15;        // supports cnt <= 2048/expert (bal. ~1040)
  const int grp = s_ >> 4;       // 0..63
  const int gid = grp * 8 + xcd; // 0..511
  const int e = gid >> 6;
  const int nt = gid & 63;

  const int off_e = offs[e];
  const int cnt = offs[e + 1] - off_e;
  if (mt * 128 >= cnt) return;
  const int nbase = nt * 64;

  __shared__ ushort As[128 * 32];  // 8 KB
  __shared__ ushort Bh[64 * 32];   // 4 KB
  __shared__ ushort Bg[64 * 32];   // 4 KB

  const int tid = threadIdx.x;
  const int wave = tid >> 6;
  const int lane = tid & 63;
  const int wm = wave & 1;
  const int wn = wave >> 1;

  const ushort* Ap = xg + (long)(off_e + mt * 128) * DM;
  const ushort* Bhp = Wt01 + (long)e * (2 * DH) * DM + (long)nbase * DM;
  const ushort* Bgp = Bhp + (long)DH * DM;

  f32x4 acc_h[4][2], acc_g[4][2];
#pragma unroll
  for (int i = 0; i < 4; i++)
#pragma unroll
    for (int j = 0; j < 2; j++) {
      acc_h[i][j] = (f32x4){0.f, 0.f, 0.f, 0.f};
      acc_g[i][j] = (f32x4){0.f, 0.f, 0.f, 0.f};
    }

  const int soff0 = wave * 1024 + lane * 16;  // bytes

  for (int k0 = 0; k0 < DM; k0 += 32) {
    __syncthreads();
    {
      // A: 8 KB = 2 chunks/wave
#pragma unroll
      for (int s = 0; s < 2; s++) {
        int off = s * 4096 + soff0;
        int r = off >> 6;
        int ie = (off & 63) >> 1;
        GL2LDS(Ap + (long)r * DM + k0 + ie, (char*)As + off);
      }
      // Bh/Bg: 4 KB each = 1 chunk/wave
      int r = soff0 >> 6;
      int ie = (soff0 & 63) >> 1;
      GL2LDS(Bhp + (long)r * DM + k0 + ie, (char*)Bh + soff0);
      GL2LDS(Bgp + (long)r * DM + k0 + ie, (char*)Bg + soff0);
    }
    __syncthreads();

    bf16x8 af[4], bhf[2], bgf[2];
#pragma unroll
    for (int i = 0; i < 4; i++) {
      int ro = (wm * 64 + i * 16 + (lane & 15)) * 32 + (lane >> 4) * 8;
      af[i] = *(const bf16x8*)&As[ro];
    }
#pragma unroll
    for (int j = 0; j < 2; j++) {
      int rb = (wn * 32 + j * 16 + (lane & 15)) * 32 + (lane >> 4) * 8;
      bhf[j] = *(const bf16x8*)&Bh[rb];
      bgf[j] = *(const bf16x8*)&Bg[rb];
    }
#pragma unroll
    for (int i = 0; i < 4; i++)
#pragma unroll
      for (int j = 0; j < 2; j++) {
        acc_h[i][j] = __builtin_amdgcn_mfma_f32_16x16x32_bf16(af[i], bhf[j], acc_h[i][j], 0, 0, 0);
        acc_g[i][j] = __builtin_amdgcn_mfma_f32_16x16x32_bf16(af[i], bgf[j], acc_g[i][j], 0, 0, 0);
      }
  }

#pragma unroll
  for (int j = 0; j < 2; j++) {
    const int col = nbase + wn * 32 + j * 16 + (lane & 15);
    const float bb0 = b0[e * DH + col];
    const float bb1 = b1[e * DH + col];
#pragma unroll
    for (int i = 0; i < 4; i++) {
#pragma unroll
      for (int r = 0; r < 4; r++) {
        int mlocal = mt * 128 + wm * 64 + i * 16 + (lane >> 4) * 4 + r;
        if (mlocal < cnt) {
          float h = acc_h[i][j][r] + bb0;
          float g = acc_g[i][j][r] + bb1;
          float a = h * (g / (1.f + __expf(-g)));
          aout[(long)(off_e + mlocal) * DH + col] = f2bf(a);
        }
      }
    }
  }
}

// ---------------- GEMM2 (split-K=2): a[rows,4096] x W2t -> partials ----
__global__ __launch_bounds__(256, 3) void gemm2_kernel(
    const ushort* __restrict__ aout, const ushort* __restrict__ W2t,
    const int* __restrict__ offs, const int* __restrict__ rmeta,
    const float* __restrict__ rw, float* __restrict__ ybuf)
{
  const int flat = blockIdx.x + 16 * (blockIdx.y + 16 * blockIdx.z);
  const int xcd = flat & 7;
  const int s_ = flat >> 3;      // 0..255
  const int mt = s_ & 15;
  const int grp = s_ >> 4;       // 0..15
  const int gid = grp * 8 + xcd; // 0..127
  const int e = gid >> 4;
  const int rest = gid & 15;
  const int nt = rest >> 1;      // 0..7
  const int kc = rest & 1;

  const int off_e = offs[e];
  const int cnt = offs[e + 1] - off_e;
  if (mt * 128 >= cnt) return;
  const int nbase = nt * 128;

  __shared__ ushort As[128 * 32];
  __shared__ ushort Bs[128 * 32];

  const int tid = threadIdx.x;
  const int wave = tid >> 6;
  const int lane = tid & 63;
  const int wm = wave & 1;
  const int wn = wave >> 1;

  const ushort* Ap = aout + (long)(off_e + mt * 128) * DH;
  const ushort* Bp = W2t + (long)e * DM * DH + (long)nbase * DH;

  f32x4 acc[4][4];
#pragma unroll
  for (int i = 0; i < 4; i++)
#pragma unroll
    for (int j = 0; j < 4; j++) acc[i][j] = (f32x4){0.f, 0.f, 0.f, 0.f};

  const int soff0 = wave * 1024 + lane * 16;
  const int kbase = kc * 2048;

  for (int k0 = kbase; k0 < kbase + 2048; k0 += 32) {
    __syncthreads();
#pragma unroll
    for (int s = 0; s < 2; s++) {
      int off = s * 4096 + soff0;
      int r = off >> 6;
      int ie = (off & 63) >> 1;
      long gelem = (long)r * DH + k0 + ie;
      GL2LDS(Ap + gelem, (char*)As + off);
      GL2LDS(Bp + gelem, (char*)Bs + off);
    }
    __syncthreads();

    bf16x8 af[4], bfr[4];
#pragma unroll
    for (int i = 0; i < 4; i++) {
      int ro = (i * 16 + (lane & 15)) * 32 + (lane >> 4) * 8;
      af[i]  = *(const bf16x8*)&As[(wm * 64) * 32 + ro];
      bfr[i] = *(const bf16x8*)&Bs[(wn * 64) * 32 + ro];
    }
#pragma unroll
    for (int i = 0; i < 4; i++)
#pragma unroll
      for (int j = 0; j < 4; j++)
        acc[i][j] = __builtin_amdgcn_mfma_f32_16x16x32_bf16(af[i], bfr[j], acc[i][j], 0, 0, 0);
  }

#pragma unroll
  for (int j = 0; j < 4; j++) {
    const int col = nbase + wn * 64 + j * 16 + (lane & 15);
#pragma unroll
    for (int i = 0; i < 4; i++) {
#pragma unroll
      for (int r = 0; r < 4; r++) {
        int mlocal = mt * 128 + wm * 64 + i * 16 + (lane >> 4) * 4 + r;
        if (mlocal < cnt) {
          int grow = off_e + mlocal;
          ybuf[((long)kc * 8192 + rmeta[grow]) * DM + col] = rw[grow] * acc[i][j][r];
        }
      }
    }
  }
}

// ---------------- combine: split-K partials + both experts + bias ----------
__global__ __launch_bounds__(256) void combine_kernel(
    const float* __restrict__ ybuf, const int* __restrict__ tkE,
    const float* __restrict__ tkW, const float* __restrict__ b2,
    float* __restrict__ out)
{
  const int t = blockIdx.x;
  const int c = threadIdx.x * 4;
  const int ee = tkE[t];
  const int e0 = ee & 0xff, e1 = ee >> 8;
  const float w0 = tkW[2 * t], w1 = tkW[2 * t + 1];

  float4 acc = {0.f, 0.f, 0.f, 0.f};
#pragma unroll
  for (int kc = 0; kc < 2; kc++) {
#pragma unroll
    for (int k = 0; k < 2; k++) {
      const float4 v = *(const float4*)&ybuf[((long)kc * 8192 + 2 * t + k) * DM + c];
      acc.x += v.x; acc.y += v.y; acc.z += v.z; acc.w += v.w;
    }
  }
  const float4 p0 = *(const float4*)&b2[(long)e0 * DM + c];
  const float4 p1 = *(const float4*)&b2[(long)e1 * DM + c];
  acc.x += w0 * p0.x + w1 * p1.x;
  acc.y += w0 * p0.y + w1 * p1.y;
  acc.z += w0 * p0.z + w1 * p1.z;
  acc.w += w0 * p0.w + w1 * p1.w;
  *(float4*)&out[(long)t * DM + c] = acc;
}

extern "C" void kernel_launch(void* const* d_in, const int* in_sizes, int n_in,
                              void* d_out, int out_size, void* d_ws, size_t ws_size,
                              hipStream_t stream) {
  const float* x  = (const float*)d_in[0];
  const float* Wg = (const float*)d_in[1];
  const float* bg = (const float*)d_in[2];
  const float* W0 = (const float*)d_in[3];
  const float* b0 = (const float*)d_in[4];
  const float* W1 = (const float*)d_in[5];
  const float* b1 = (const float*)d_in[6];
  const float* W2 = (const float*)d_in[7];
  const float* b2 = (const float*)d_in[8];
  float* out = (float*)d_out;

  char* ws = (char*)d_ws;
  // ybuf ALIASES Wt01: Wt01 dead after gemm1; ybuf written by gemm2 after.
  ushort* Wt01 = (ushort*)(ws + 0);           // [8][8192][1024] bf16 = 134217728
  float*  ybuf = (float*)(ws + 0);            // [2][8192][1024] f32 =  67108864
  ushort* W2t  = (ushort*)(ws + 134217728);   // [8][1024][4096] bf16 = 67108864
  ushort* xg   = (ushort*)(ws + 201326592);   // [8320][1024] bf16
  ushort* aout = (ushort*)(ws + 218365952);   // [8320][4096] bf16
  int*    tkE  = (int*)(ws + 320077824);
  float*  tkW  = (float*)(ws + 320094208);
  int*    rmeta= (int*)(ws + 320126976);
  float*  rw   = (float*)(ws + 320160256);
  int*    gcnt = (int*)(ws + 320193536);
  int*    offs = gcnt + 8;
  int*    cursor = gcnt + 20;

  hipMemsetAsync(gcnt, 0, 32, stream);
  gate_kernel<<<NTOK / 4, 256, 0, stream>>>(x, Wg, bg, tkE, tkW, gcnt);
  scan_kernel<<<1, 64, 0, stream>>>(gcnt, offs, cursor);
  build_kernel<<<NTOK / 256, 256, 0, stream>>>(tkE, tkW, offs, cursor, rmeta, rw);
  gather_kernel<<<2 * NTOK, 256, 0, stream>>>(x, rmeta, xg);

  transpose_cvt<<<dim3(64, 16, 8), 256, 0, stream>>>(
      W0, Wt01, 1024, 4096, (long)1024 * 4096, (long)8192 * 1024);
  transpose_cvt<<<dim3(64, 16, 8), 256, 0, stream>>>(
      W1, Wt01 + (long)4096 * 1024, 1024, 4096, (long)1024 * 4096, (long)8192 * 1024);
  transpose_cvt<<<dim3(16, 64, 8), 256, 0, stream>>>(
      W2, W2t, 4096, 1024, (long)4096 * 1024, (long)1024 * 4096);

  gemm1_kernel<<<dim3(16, 64, 8), 256, 0, stream>>>(xg, Wt01, b0, b1, offs, aout);
  gemm2_kernel<<<dim3(16, 16, 8), 256, 0, stream>>>(aout, W2t, offs, rmeta, rw, ybuf);
  combine_kernel<<<dim3(NTOK), 256, 0, stream>>>(ybuf, tkE, tkW, b2, out);
}